// Round 4
// baseline (233.029 us; speedup 1.0000x reference)
//
#include <hip/hip_runtime.h>

// ChannelAttention on MI355X (gfx950)
// B=128, HW=256 (=16x16), C=1024, S=32, EMB=256, IDF=256(==HW)
//
// out[b,p,c] = sum_s we[b,s,p] * softmax_s( sum_p' wc[b,p',c] * we[b,s,p'] )
// attn[b,c,s] = softmax probabilities
//
// d_out: out (128*256*1024 f32) then attn (128*1024*32 f32)
// d_ws : weT[b][p][s] (4 MB) — transposed projection: consumers read a
//        lane-uniform contiguous 128B row per p -> scalar s_load (free pipe).
//
// R3: reduction-free c-slicing (thread owns 1 channel, all 256 p; zero LDS)
// + explicit 2-stage ping-pong prefetch: 16 wc loads for group g+1 issued
// before the 512 FMAs of group g (1024 cyc VALU cover vs ~900 cyc HBM).
// R0/R2 lesson: occupancy was never binding; per-wave load pipelining was.

namespace {
constexpr int kB  = 128;
constexpr int kHW = 256;
constexpr int kC  = 1024;
constexpr int kS  = 32;
constexpr int kE  = 256;
}

// weT[b][p][s] = bias[p] + sum_e emb[b][s][e] * K[e][p]
// grid (4,128): blockIdx.x = s-octet, 256 thr = p. Ping-pong K prefetch.
__global__ __launch_bounds__(256) void we_proj_kernel(
    const float* __restrict__ emb, const float* __restrict__ K,
    const float* __restrict__ bias, float* __restrict__ weT) {
  const int b  = blockIdx.y;
  const int sq = blockIdx.x;
  const int p  = threadIdx.x;
  const float* embb = emb + (size_t)b * kS * kE + (size_t)sq * 8 * kE;

  float acc[8];
#pragma unroll
  for (int j = 0; j < 8; ++j) acc[j] = 0.f;

  float kA[8], kB2[8];
#pragma unroll
  for (int u = 0; u < 8; ++u) kA[u] = K[u * kHW + p];   // group 0

  for (int e0 = 0; e0 < kE; e0 += 16) {
    // prefetch group (e0+8..e0+15) into kB2, compute with kA
#pragma unroll
    for (int u = 0; u < 8; ++u) kB2[u] = K[(e0 + 8 + u) * kHW + p];
#pragma unroll
    for (int u = 0; u < 8; ++u) {
      const float kv = kA[u];
#pragma unroll
      for (int j = 0; j < 8; ++j)                 // embb[...]: scalar loads
        acc[j] = fmaf(embb[j * kE + e0 + u], kv, acc[j]);
    }
    // prefetch group (e0+16..e0+23) into kA (guarded), compute with kB2
    if (e0 + 16 < kE) {
#pragma unroll
      for (int u = 0; u < 8; ++u) kA[u] = K[(e0 + 16 + u) * kHW + p];
    }
#pragma unroll
    for (int u = 0; u < 8; ++u) {
      const float kv = kB2[u];
#pragma unroll
      for (int j = 0; j < 8; ++j)
        acc[j] = fmaf(embb[j * kE + e0 + 8 + u], kv, acc[j]);
    }
  }

  const float bv = bias[p];
  float4* dst = (float4*)(weT + ((size_t)b * kHW + p) * kS + sq * 8);
  dst[0] = make_float4(acc[0] + bv, acc[1] + bv, acc[2] + bv, acc[3] + bv);
  dst[1] = make_float4(acc[4] + bv, acc[5] + bv, acc[6] + bv, acc[7] + bv);
}

// grid (4,128), 256 thr: thread owns channel c = bx*256+tid, all 256 p.
__global__ __launch_bounds__(256) void attn_kernel(
    const float* __restrict__ wc, const float* __restrict__ weT,
    float* __restrict__ out, float* __restrict__ attn_out) {
  const int b = blockIdx.y;
  const int c = blockIdx.x * 256 + threadIdx.x;
  const float* wcb  = wc  + (size_t)b * kHW * kC;
  const float* weTb = weT + (size_t)b * kHW * kS;

  // ---- Phase A: logits[s] = sum_p wc[p][c] * weT[p][s], 16-deep pipeline --
  float acc[kS];
#pragma unroll
  for (int s = 0; s < kS; ++s) acc[s] = 0.f;

  float wA[16], wB[16];
#pragma unroll
  for (int u = 0; u < 16; ++u)                       // prologue: group 0
    wA[u] = wcb[(size_t)u * kC + c];

  for (int g = 0; g < 16; g += 2) {
    const int pA = g * 16, pB = pA + 16, pN = pA + 32;
    // prefetch group g+1, consume group g
#pragma unroll
    for (int u = 0; u < 16; ++u)
      wB[u] = wcb[(size_t)(pB + u) * kC + c];
#pragma unroll
    for (int u = 0; u < 16; ++u) {
      const float* wr = weTb + (size_t)(pA + u) * kS;  // uniform -> s_load
      const float wv = wA[u];
#pragma unroll
      for (int s = 0; s < kS; ++s)
        acc[s] = fmaf(wr[s], wv, acc[s]);
    }
    // prefetch group g+2 (guarded), consume group g+1
    if (pN < kHW) {
#pragma unroll
      for (int u = 0; u < 16; ++u)
        wA[u] = wcb[(size_t)(pN + u) * kC + c];
    }
#pragma unroll
    for (int u = 0; u < 16; ++u) {
      const float* wr = weTb + (size_t)(pB + u) * kS;
      const float wv = wB[u];
#pragma unroll
      for (int s = 0; s < kS; ++s)
        acc[s] = fmaf(wr[s], wv, acc[s]);
    }
  }

  // ---- softmax over s (per-thread, in registers) ----
  float m = acc[0];
#pragma unroll
  for (int s = 1; s < kS; ++s) m = fmaxf(m, acc[s]);
  float sum = 0.f;
#pragma unroll
  for (int s = 0; s < kS; ++s) {
    acc[s] = __expf(acc[s] - m);
    sum += acc[s];
  }
  const float inv = 1.0f / sum;
#pragma unroll
  for (int s = 0; s < kS; ++s) acc[s] *= inv;

  // ---- attn[b][c][0..31]: 128B contiguous per thread ----
  float4* ap = (float4*)(attn_out + ((size_t)b * kC + c) * kS);
#pragma unroll
  for (int s4 = 0; s4 < kS / 4; ++s4)
    ap[s4] = make_float4(acc[4 * s4], acc[4 * s4 + 1],
                         acc[4 * s4 + 2], acc[4 * s4 + 3]);

  // ---- Phase B: out[p][c] = sum_s weT[p][s] * prob[s] ----
  float* outb = out + (size_t)b * kHW * kC;
  for (int g = 0; g < 16; ++g) {
#pragma unroll
    for (int u = 0; u < 16; ++u) {
      const int p = g * 16 + u;
      const float* wr = weTb + (size_t)p * kS;       // uniform -> s_load
      float o = 0.f;
#pragma unroll
      for (int s = 0; s < kS; ++s)
        o = fmaf(wr[s], acc[s], o);
      outb[(size_t)p * kC + c] = o;                  // coalesced store
    }
  }
}

extern "C" void kernel_launch(void* const* d_in, const int* in_sizes, int n_in,
                              void* d_out, int out_size, void* d_ws, size_t ws_size,
                              hipStream_t stream) {
  const float* wc   = (const float*)d_in[0];
  const float* emb  = (const float*)d_in[1];
  const float* K    = (const float*)d_in[2];
  const float* bias = (const float*)d_in[3];

  float* out  = (float*)d_out;
  float* attn = out + (size_t)kB * kHW * kC;
  float* weT  = (float*)d_ws;

  we_proj_kernel<<<dim3(4, kB), 256, 0, stream>>>(emb, K, bias, weT);
  attn_kernel<<<dim3(4, kB), 256, 0, stream>>>(wc, weT, out, attn);
}